// Round 9
// baseline (111.040 us; speedup 1.0000x reference)
//
#include <hip/hip_runtime.h>

// ChamferLoss: prediction [B,N,3] f32, target [B,M,3] f32 -> scalar f32.
// Model (R5-R7 calibrated): wall = VALU-issue (pk ~4cyc/instr) + LDS-pipe
// (12 cyc/b128), SERIALIZED; LDS reads/CU = 32768/RPT.
// v9: RPT=16 at 4 blocks/CU (MC=128, 1024 blocks). VGPRs contained via
// VOP3P op_sel broadcast: per row only (qx,qy) pair + (qz,x2) pair + best.

#define BLOCK 256
#define RPT   16     // rows per thread
#define MC    128    // Y points per LDS chunk
#define NPTS  8192   // N == M
#define NCH   (NPTS / MC)   // 64 chunks
#define NB    4      // batch

typedef float v2f __attribute__((ext_vector_type(2)));
typedef float v4f __attribute__((ext_vector_type(4)));

__device__ __forceinline__ float min3f(float a, float b, float c) {
    float d;
    asm("v_min3_f32 %0, %1, %2, %3" : "=v"(d) : "v"(a), "v"(b), "v"(c));
    return d;
}
// d[lo] = P.lo*b.lo + c.lo ; d[hi] = P.lo*b.hi + c.hi   (broadcast src0 LO)
__device__ __forceinline__ v2f pk_fma_bl(v2f P, v2f b, v2f c) {
    v2f d;
    asm("v_pk_fma_f32 %0, %1, %2, %3 op_sel:[0,0,0] op_sel_hi:[0,1,1]"
        : "=v"(d) : "v"(P), "v"(b), "v"(c));
    return d;
}
// d[lo] = P.hi*b.lo + c.lo ; d[hi] = P.hi*b.hi + c.hi   (broadcast src0 HI)
__device__ __forceinline__ v2f pk_fma_bh(v2f P, v2f b, v2f c) {
    v2f d;
    asm("v_pk_fma_f32 %0, %1, %2, %3 op_sel:[1,0,0] op_sel_hi:[1,1,1]"
        : "=v"(d) : "v"(P), "v"(b), "v"(c));
    return d;
}

__global__ __launch_bounds__(BLOCK) void chamfer_min_fused(
    const float* __restrict__ pred, const float* __restrict__ targ,
    float* __restrict__ pA,          // [B, NCH, N] partials, dir pred->targ
    float* __restrict__ pB,          // [B, NCH, M] partials, dir targ->pred
    double* __restrict__ acc, unsigned int* __restrict__ counter) {
    if (blockIdx.x == 0 && blockIdx.y == 0 && blockIdx.z == 0 && threadIdx.x == 0) {
        *acc = 0.0;            // stream order: done before reduce starts
        *counter = 0u;
    }

    const int z   = blockIdx.z;       // 0..2B-1: dir = z>>2, b = z&3
    const int dir = z >> 2, b = z & (NB - 1);
    const float* X = dir ? targ : pred;
    const float* Y = dir ? pred : targ;
    float* partial = dir ? pB : pA;

    // Pair-packed chunk: points (2p,2p+1):
    //   ldsA[p] = (x0,x1,y0,y1), ldsB[p] = (z0,z1,w0,w1), w = ||y||^2.
    __shared__ v4f ldsA[MC / 2];
    __shared__ v4f ldsB[MC / 2];
    const int mc = blockIdx.y;

    if (threadIdx.x < MC / 2) {
        const int p = threadIdx.x;
        const float* yp = Y + ((size_t)b * NPTS + (size_t)mc * MC + 2 * p) * 3;
        float ax = yp[0], ay = yp[1], az = yp[2];
        float bx = yp[3], by = yp[4], bz = yp[5];
        float aw = fmaf(ax, ax, fmaf(ay, ay, az * az));
        float bw = fmaf(bx, bx, fmaf(by, by, bz * bz));
        ldsA[p] = (v4f){ax, bx, ay, by};
        ldsB[p] = (v4f){az, bz, aw, bw};
    }
    __syncthreads();

    const int row0 = blockIdx.x * (BLOCK * RPT);
    v2f Pxy[RPT];   // (qx, qy) = (-2px, -2py)
    v2f Pzw[RPT];   // (qz, x2) = (-2pz, ||x||^2)
    float best[RPT];
#pragma unroll
    for (int r = 0; r < RPT; ++r) {
        int row = row0 + r * BLOCK + threadIdx.x;
        const float* xp = X + ((size_t)b * NPTS + row) * 3;
        float px = xp[0], py = xp[1], pz = xp[2];
        Pxy[r] = (v2f){-2.0f * px, -2.0f * py};
        Pzw[r] = (v2f){-2.0f * pz, fmaf(px, px, fmaf(py, py, pz * pz))};
        best[r] = 3.0e38f;
    }

    // Main loop: one 4-point group per iter (4 broadcast ds_read_b128,
    // conflict-free), 16 rows each: per 4 points per row
    // 6 pk_fma (op_sel-broadcast q) + 2 min3 = 2 VALU instr/pair.
#pragma unroll 2
    for (int j = 0; j < MC / 2; j += 2) {
        v4f A0 = ldsA[j],     B0 = ldsB[j];
        v4f A1 = ldsA[j + 1], B1 = ldsB[j + 1];
        v2f x01 = __builtin_shufflevector(A0, A0, 0, 1);
        v2f y01 = __builtin_shufflevector(A0, A0, 2, 3);
        v2f z01 = __builtin_shufflevector(B0, B0, 0, 1);
        v2f w01 = __builtin_shufflevector(B0, B0, 2, 3);
        v2f x23 = __builtin_shufflevector(A1, A1, 0, 1);
        v2f y23 = __builtin_shufflevector(A1, A1, 2, 3);
        v2f z23 = __builtin_shufflevector(B1, B1, 0, 1);
        v2f w23 = __builtin_shufflevector(B1, B1, 2, 3);
#pragma unroll
        for (int r = 0; r < RPT; ++r) {
            v2f t0 = pk_fma_bl(Pzw[r], z01, w01);   // qz*z + w
            t0 = pk_fma_bh(Pxy[r], y01, t0);        // + qy*y
            t0 = pk_fma_bl(Pxy[r], x01, t0);        // + qx*x
            v2f t1 = pk_fma_bl(Pzw[r], z23, w23);
            t1 = pk_fma_bh(Pxy[r], y23, t1);
            t1 = pk_fma_bl(Pxy[r], x23, t1);
            best[r] = min3f(best[r], t0.x, t0.y);
            best[r] = min3f(best[r], t1.x, t1.y);
        }
    }

    // Coalesced per-chunk partial write (clamp + ||x||^2 folded in).
#pragma unroll
    for (int r = 0; r < RPT; ++r) {
        int row = row0 + r * BLOCK + threadIdx.x;
        partial[((size_t)b * NCH + mc) * NPTS + row] = fmaxf(best[r] + Pzw[r].y, 0.0f);
    }
}

// 64 blocks x 256 threads, 4 rows/thread via float4 loads: min over NCH chunk
// partials per row, sum in double, atomicAdd; last block writes the scalar.
__global__ __launch_bounds__(256) void chamfer_reduce(
    const float* __restrict__ pA, const float* __restrict__ pB,
    double* __restrict__ acc, unsigned int* __restrict__ counter,
    float* __restrict__ out) {
    const int g = blockIdx.x * 256 + threadIdx.x;   // thread id over 16384
    const int r4 = g * 4;                           // first of 4 rows
    const int half = NB * NPTS;                     // 32768 rows per direction
    const float* src = (r4 < half) ? pA : pB;
    const int gg = r4 & (half - 1);
    const int b = gg >> 13, r = gg & (NPTS - 1);

    v4f vb = (v4f){3.0e38f, 3.0e38f, 3.0e38f, 3.0e38f};
#pragma unroll 8
    for (int c = 0; c < NCH; ++c) {
        v4f v = *(const v4f*)(src + ((size_t)b * NCH + c) * NPTS + r);
        vb.x = fminf(vb.x, v.x);
        vb.y = fminf(vb.y, v.y);
        vb.z = fminf(vb.z, v.z);
        vb.w = fminf(vb.w, v.w);
    }

    double d = (double)vb.x + (double)vb.y + (double)vb.z + (double)vb.w;
    for (int off = 32; off > 0; off >>= 1) d += __shfl_down(d, off);
    __shared__ double sh[4];
    const int lane = threadIdx.x & 63, wid = threadIdx.x >> 6;
    if (lane == 0) sh[wid] = d;
    __syncthreads();

    if (threadIdx.x == 0) {
        double blocktotal = sh[0] + sh[1] + sh[2] + sh[3];
        atomicAdd(acc, blocktotal);
        __threadfence();
        unsigned int ticket = atomicAdd(counter, 1u);
        if (ticket == gridDim.x - 1) {
            __threadfence();
            double s = atomicAdd(acc, 0.0);   // coherent read of final sum
            out[0] = (float)(s / (double)(NB * NPTS));  // both dirs /32768
        }
    }
}

extern "C" void kernel_launch(void* const* d_in, const int* in_sizes, int n_in,
                              void* d_out, int out_size, void* d_ws, size_t ws_size,
                              hipStream_t stream) {
    const float* pred = (const float*)d_in[0];  // [B, N, 3]
    const float* targ = (const float*)d_in[1];  // [B, M, 3]
    float* out = (float*)d_out;

    float* pA = (float*)d_ws;                               // 8.4 MB
    float* pB = pA + (size_t)NB * NCH * NPTS;               // 8.4 MB
    double* acc = (double*)(pB + (size_t)NB * NCH * NPTS);
    unsigned int* counter = (unsigned int*)(acc + 1);

    // Both directions in one dispatch: grid.z = 2*B (dir, batch).
    // 1024 blocks = 4 blocks/CU = 4 waves/SIMD.
    dim3 g1(NPTS / (BLOCK * RPT), NCH, 2 * NB);             // (2, 64, 8)
    chamfer_min_fused<<<g1, BLOCK, 0, stream>>>(pred, targ, pA, pB, acc, counter);

    const int nblk = (2 * NB * NPTS / 4) / 256;             // 64
    chamfer_reduce<<<nblk, 256, 0, stream>>>(pA, pB, acc, counter, out);
}